// Round 1
// 1523.473 us; speedup vs baseline: 1.1487x; 1.1487x over previous
//
#include <hip/hip_runtime.h>

#define NU 100000
#define NI 100000
#define NE 500000
#define HD 128

using bf16x8 = __attribute__((ext_vector_type(8))) __bf16;
using f32x4  = __attribute__((ext_vector_type(4))) float;

// ---------------- src-degree histograms (3 arrays; dst degrees come from CSR cnt) ----
__global__ __launch_bounds__(256) void src_count(
    const int* __restrict__ s0, const int* __restrict__ s1,
    const int* __restrict__ s2, float* __restrict__ deg)
{
    long long t = (long long)blockIdx.x * 256 + threadIdx.x;
    if (t >= 3LL * NE) return;
    int a = (int)(t / NE);
    int e = (int)(t - (long long)a * NE);
    const int* p = (a == 0) ? s0 : (a == 1) ? s1 : s2;
    // slots: 0 -> rs_out_uu, 200000 -> rs_out_ui, 400000 -> rs_out_iu
    atomicAdd(&deg[a * 200000 + p[e]], 1.0f);
}

__global__ __launch_bounds__(256) void deg_finalize(float* __restrict__ deg)
{
    int t = blockIdx.x * 256 + threadIdx.x;
    if (t < 600000) deg[t] = rsqrtf(fmaxf(deg[t], 1.0f));
}

__global__ __launch_bounds__(256) void rs_from_cnt(const int* __restrict__ cnt,
                                                   float* __restrict__ rs, int n)
{
    int t = blockIdx.x * 256 + threadIdx.x;
    if (t < n) rs[t] = rsqrtf(fmaxf((float)cnt[t], 1.0f));
}

// ---------------- CSR build ----------------
__global__ __launch_bounds__(256) void count_dst(const int* __restrict__ dst,
                                                 int* __restrict__ cnt)
{
    int e = blockIdx.x * 256 + threadIdx.x;
    if (e < NE) atomicAdd(&cnt[dst[e]], 1);
}

__global__ __launch_bounds__(256) void scan_block(const int* __restrict__ cnt, int n,
                                                  int* __restrict__ rp,
                                                  int* __restrict__ bsum)
{
    __shared__ int s[256];
    int gid = blockIdx.x * 256 + threadIdx.x;
    int v = (gid < n) ? cnt[gid] : 0;
    s[threadIdx.x] = v;
    __syncthreads();
#pragma unroll
    for (int off = 1; off < 256; off <<= 1) {
        int t = (threadIdx.x >= off) ? s[threadIdx.x - off] : 0;
        __syncthreads();
        s[threadIdx.x] += t;
        __syncthreads();
    }
    if (gid < n) rp[gid] = s[threadIdx.x] - v;   // exclusive
    if (threadIdx.x == 255) bsum[blockIdx.x] = s[255];
}

__global__ __launch_bounds__(512) void scan_bsums(int* __restrict__ bsum, int nb)
{
    __shared__ int s[512];
    int v = (threadIdx.x < nb) ? bsum[threadIdx.x] : 0;
    s[threadIdx.x] = v;
    __syncthreads();
#pragma unroll
    for (int off = 1; off < 512; off <<= 1) {
        int t = (threadIdx.x >= off) ? s[threadIdx.x - off] : 0;
        __syncthreads();
        s[threadIdx.x] += t;
        __syncthreads();
    }
    if (threadIdx.x < nb) bsum[threadIdx.x] = s[threadIdx.x] - v;
    if (threadIdx.x == 0) bsum[nb] = s[nb - 1];  // total
}

__global__ __launch_bounds__(256) void scan_add(int* __restrict__ rp,
                                                const int* __restrict__ bsum,
                                                int n, int nb)
{
    int gid = blockIdx.x * 256 + threadIdx.x;
    if (gid < n) rp[gid] += bsum[blockIdx.x];
    if (gid == 0) rp[n] = bsum[nb];
}

__global__ __launch_bounds__(256) void csr_fill(const int* __restrict__ src,
                                                const int* __restrict__ dst,
                                                const int* __restrict__ rp,
                                                int* __restrict__ cursor,
                                                int* __restrict__ eidx)
{
    int e = blockIdx.x * 256 + threadIdx.x;
    if (e >= NE) return;
    int d = dst[e];
    int pos = rp[d] + atomicAdd(&cursor[d], 1);
    eidx[pos] = src[e];
}

// ---------------- CSR gather: m[d] = sum_{e in csr[d]} x[src_e] * rs[src_e] --------
__global__ __launch_bounds__(256) void gather_scaled(
    const float* __restrict__ x, const float* __restrict__ rs,
    const int* __restrict__ rp, const int* __restrict__ eidx,
    float* __restrict__ m, int n)
{
    int row = blockIdx.x * 8 + (threadIdx.x >> 5);
    int c = (threadIdx.x & 31) * 4;
    if (row >= n) return;
    int beg = rp[row], end = rp[row + 1];
    float ax = 0.f, ay = 0.f, az = 0.f, aw = 0.f;
    for (int p = beg; p < end; ++p) {
        int s = eidx[p];
        float sc = rs[s];
        float4 v = *(const float4*)(x + (long long)s * HD + c);
        ax = fmaf(v.x, sc, ax);
        ay = fmaf(v.y, sc, ay);
        az = fmaf(v.z, sc, az);
        aw = fmaf(v.w, sc, aw);
    }
    *(float4*)(m + (long long)row * HD + c) = make_float4(ax, ay, az, aw);
}

// ---------------- W pre-pass: fp32 [K x 128] -> transposed bf16 hi/lo [128 x Kpad] ----
__global__ __launch_bounds__(256) void convert_w(
    const float* __restrict__ W, int K, int Kpad,
    __bf16* __restrict__ Wh, __bf16* __restrict__ Wl)
{
    int t = blockIdx.x * 256 + threadIdx.x;
    if (t >= 128 * Kpad) return;
    int k = t >> 7;
    int n = t & 127;
    float x = (k < K) ? W[k * 128 + n] : 0.f;
    __bf16 h = (__bf16)x;
    float r = x - (float)h;
    Wh[n * Kpad + k] = h;
    Wl[n * Kpad + k] = (__bf16)r;
}

// ---------------- C[M x 128] = A[M x K] @ W[K x 128] via split-bf16 MFMA ------------
// A fp32 (converted to hi/lo bf16 in-kernel during LDS staging).
// (hi+lo)*(hi+lo) ~= hi*hi + hi*lo + lo*hi  (lo*lo ~ 2^-18 rel, dropped)
__global__ __launch_bounds__(256) void gemm128_mfma(
    const float* __restrict__ A, int K, int Kpad, int M,
    const __bf16* __restrict__ Wh, const __bf16* __restrict__ Wl,
    const float* __restrict__ bias,
    const float* __restrict__ out_scale,
    int do_relu, int do_accum,
    float* __restrict__ C)
{
    // padded row stride 40 bf16 (80B) to spread banks for ds_read_b128
    __shared__ __bf16 sAh[64 * 40];
    __shared__ __bf16 sAl[64 * 40];
    __shared__ __bf16 sWh[128 * 40];
    __shared__ __bf16 sWl[128 * 40];

    const int tid  = threadIdx.x;
    const int row0 = blockIdx.x * 64;
    const int lane = tid & 63;
    const int wv   = tid >> 6;    // wave 0..3 -> 32-col slice
    const int lr   = lane & 15;
    const int lq   = lane >> 4;   // quarter 0..3

    f32x4 acc[4][2];
#pragma unroll
    for (int i = 0; i < 4; ++i)
#pragma unroll
        for (int j = 0; j < 2; ++j)
#pragma unroll
            for (int t = 0; t < 4; ++t) acc[i][j][t] = 0.f;

    const int arow  = tid >> 2;         // 0..63
    const int akoff = (tid & 3) << 3;   // 0,8,16,24
    const int wcol  = tid >> 1;         // 0..127
    const int wkoff = (tid & 1) << 4;   // 0,16

    const int nk = Kpad >> 5;
    for (int kc = 0; kc < nk; ++kc) {
        const int k0 = kc << 5;
        // ---- stage A tile 64x32, fp32 -> bf16 hi/lo ----
        {
            int row = row0 + arow;
            int k = k0 + akoff;
            float f[8];
            if (row < M && k + 7 < K) {
                float4 v0 = *(const float4*)(A + (long long)row * K + k);
                float4 v1 = *(const float4*)(A + (long long)row * K + k + 4);
                f[0] = v0.x; f[1] = v0.y; f[2] = v0.z; f[3] = v0.w;
                f[4] = v1.x; f[5] = v1.y; f[6] = v1.z; f[7] = v1.w;
            } else {
#pragma unroll
                for (int t = 0; t < 8; ++t)
                    f[t] = (row < M && k + t < K) ? A[(long long)row * K + k + t] : 0.f;
            }
            bf16x8 h8, l8;
#pragma unroll
            for (int t = 0; t < 8; ++t) {
                __bf16 h = (__bf16)f[t];
                h8[t] = h;
                l8[t] = (__bf16)(f[t] - (float)h);
            }
            *(bf16x8*)(&sAh[arow * 40 + akoff]) = h8;
            *(bf16x8*)(&sAl[arow * 40 + akoff]) = l8;
        }
        // ---- stage W tile 128 cols x 32 k (already transposed bf16 in global) ----
        {
            const __bf16* ph = Wh + (long long)wcol * Kpad + k0 + wkoff;
            const __bf16* pl = Wl + (long long)wcol * Kpad + k0 + wkoff;
            bf16x8 w0 = *(const bf16x8*)(ph);
            bf16x8 w1 = *(const bf16x8*)(ph + 8);
            bf16x8 x0 = *(const bf16x8*)(pl);
            bf16x8 x1 = *(const bf16x8*)(pl + 8);
            *(bf16x8*)(&sWh[wcol * 40 + wkoff])     = w0;
            *(bf16x8*)(&sWh[wcol * 40 + wkoff + 8]) = w1;
            *(bf16x8*)(&sWl[wcol * 40 + wkoff])     = x0;
            *(bf16x8*)(&sWl[wcol * 40 + wkoff + 8]) = x1;
        }
        __syncthreads();
        // ---- MFMA: wave wv covers cols [wv*32, wv*32+32), rows 0..63 ----
        bf16x8 bh[2], bl[2];
#pragma unroll
        for (int j = 0; j < 2; ++j) {
            int c = wv * 32 + j * 16 + lr;
            bh[j] = *(const bf16x8*)(&sWh[c * 40 + lq * 8]);
            bl[j] = *(const bf16x8*)(&sWl[c * 40 + lq * 8]);
        }
#pragma unroll
        for (int i = 0; i < 4; ++i) {
            bf16x8 ah = *(const bf16x8*)(&sAh[(i * 16 + lr) * 40 + lq * 8]);
            bf16x8 al = *(const bf16x8*)(&sAl[(i * 16 + lr) * 40 + lq * 8]);
#pragma unroll
            for (int j = 0; j < 2; ++j) {
                acc[i][j] = __builtin_amdgcn_mfma_f32_16x16x32_bf16(ah, bh[j], acc[i][j], 0, 0, 0);
                acc[i][j] = __builtin_amdgcn_mfma_f32_16x16x32_bf16(ah, bl[j], acc[i][j], 0, 0, 0);
                acc[i][j] = __builtin_amdgcn_mfma_f32_16x16x32_bf16(al, bh[j], acc[i][j], 0, 0, 0);
            }
        }
        __syncthreads();
    }

    // ---- epilogue: D[row][col]: col = lane&15 (+16j+32wv), row = 4*(lane>>4)+t (+16i) ----
#pragma unroll
    for (int j = 0; j < 2; ++j) {
        int col = wv * 32 + j * 16 + lr;
        float bv = bias ? bias[col] : 0.f;
#pragma unroll
        for (int i = 0; i < 4; ++i) {
            int r0 = row0 + i * 16 + lq * 4;
#pragma unroll
            for (int t = 0; t < 4; ++t) {
                int row = r0 + t;
                if (row < M) {
                    float s = out_scale ? out_scale[row] : 1.f;
                    float v = acc[i][j][t] * s + bv;
                    if (do_relu) v = fmaxf(v, 0.f);
                    float* cp = C + (long long)row * 128 + col;
                    if (do_accum) v += *cp;
                    *cp = v;
                }
            }
        }
    }
}

static inline void build_csr(const int* src, const int* dst, int n_dst,
                             int* cnt, int* rp, int* cursor, int* eidx,
                             int* bsum, float* rs_in, hipStream_t stream)
{
    const int nb = (n_dst + 255) / 256;
    hipMemsetAsync(cnt, 0, n_dst * sizeof(int), stream);
    count_dst<<<(NE + 255) / 256, 256, 0, stream>>>(dst, cnt);
    // dst-degree rsqrt comes free from the CSR histogram (saves 1.5M global atomics)
    rs_from_cnt<<<nb, 256, 0, stream>>>(cnt, rs_in, n_dst);
    scan_block<<<nb, 256, 0, stream>>>(cnt, n_dst, rp, bsum);
    scan_bsums<<<1, 512, 0, stream>>>(bsum, nb);
    scan_add<<<nb, 256, 0, stream>>>(rp, bsum, n_dst, nb);
    hipMemsetAsync(cursor, 0, n_dst * sizeof(int), stream);
    csr_fill<<<(NE + 255) / 256, 256, 0, stream>>>(src, dst, rp, cursor, eidx);
}

extern "C" void kernel_launch(void* const* d_in, const int* in_sizes, int n_in,
                              void* d_out, int out_size, void* d_ws, size_t ws_size,
                              hipStream_t stream)
{
    const float* feat_user = (const float*)d_in[0];
    const float* feat_item = (const float*)d_in[1];
    const int* src_uu = (const int*)d_in[2];
    const int* dst_uu = (const int*)d_in[3];
    const int* src_ui = (const int*)d_in[4];
    const int* dst_ui = (const int*)d_in[5];
    const int* src_iu = (const int*)d_in[6];
    const int* dst_iu = (const int*)d_in[7];
    const float* We_u = (const float*)d_in[8];
    const float* be_u = (const float*)d_in[9];
    const float* We_i = (const float*)d_in[10];
    const float* be_i = (const float*)d_in[11];

    float* hu = (float*)d_out;                 // [NU x 128]
    float* hi = hu + (size_t)NU * HD;          // [NI x 128]

    float* ws   = (float*)d_ws;
    float* m_uu = ws;                          // [NU x 128] dst=user
    float* m_ui = m_uu + (size_t)NU * HD;      // [NI x 128] dst=item
    float* m_iu = m_ui + (size_t)NI * HD;      // [NU x 128] dst=user
    float* deg  = m_iu + (size_t)NU * HD;      // 6 x 100000
    float* rs_out_uu = deg + 0;
    float* rs_in_uu  = deg + 100000;
    float* rs_out_ui = deg + 200000;
    float* rs_in_ui  = deg + 300000;
    float* rs_out_iu = deg + 400000;
    float* rs_in_iu  = deg + 500000;

    int* ib = (int*)(deg + 600000);
    int* rp_uu   = ib;                 ib += 100001;
    int* rp_ui   = ib;                 ib += 100001;
    int* rp_iu   = ib;                 ib += 100001;
    int* ei_uu   = ib;                 ib += NE;
    int* ei_ui   = ib;                 ib += NE;
    int* ei_iu   = ib;                 ib += NE;
    int* cnt     = ib;                 ib += 100000;
    int* cursor  = ib;                 ib += 100000;
    int* bsum    = ib;                 ib += 1024;

    // bf16 hi/lo transposed weight buffers (~884 KB)
    uintptr_t wp = ((uintptr_t)ib + 63) & ~(uintptr_t)63;
    __bf16* wtbuf = (__bf16*)wp;
    __bf16* eu_h = wtbuf;                       // 128*256
    __bf16* eu_l = eu_h + 128 * 256;
    __bf16* ei_h = eu_l + 128 * 256;            // 128*320
    __bf16* ei_l = ei_h + 128 * 320;
    __bf16* lw   = ei_l + 128 * 320;            // 9 x (hi,lo) of 128*128

    // weight conversion pre-pass (tiny)
    convert_w<<<(128 * 256 + 255) / 256, 256, 0, stream>>>(We_u, 256, 256, eu_h, eu_l);
    convert_w<<<(128 * 320 + 255) / 256, 256, 0, stream>>>(We_i, 300, 320, ei_h, ei_l);
    for (int l = 0; l < 3; ++l)
        for (int e = 0; e < 3; ++e) {
            const float* W = (const float*)d_in[12 + 6 * l + 2 * e];
            __bf16* h = lw + (size_t)(l * 3 + e) * 2 * 16384;
            convert_w<<<64, 256, 0, stream>>>(W, 128, 128, h, h + 16384);
        }

    // src-degree histograms only (dst degrees derived from CSR counts)
    hipMemsetAsync(deg, 0, 600000 * sizeof(float), stream);
    src_count<<<(3 * NE + 255) / 256, 256, 0, stream>>>(src_uu, src_ui, src_iu, deg);
    deg_finalize<<<(600000 + 255) / 256, 256, 0, stream>>>(deg);

    // CSR (dst-major) per etype; each also produces rs_in_* from its histogram
    build_csr(src_uu, dst_uu, NU, cnt, rp_uu, cursor, ei_uu, bsum, rs_in_uu, stream);
    build_csr(src_ui, dst_ui, NI, cnt, rp_ui, cursor, ei_ui, bsum, rs_in_ui, stream);
    build_csr(src_iu, dst_iu, NU, cnt, rp_iu, cursor, ei_iu, bsum, rs_in_iu, stream);

    // HeteroLinear embed
    gemm128_mfma<<<(NU + 63) / 64, 256, 0, stream>>>(feat_user, 256, 256, NU,
                                                     eu_h, eu_l, be_u, nullptr, 0, 0, hu);
    gemm128_mfma<<<(NI + 63) / 64, 256, 0, stream>>>(feat_item, 300, 320, NI,
                                                     ei_h, ei_l, be_i, nullptr, 0, 0, hi);

    const int gat_blocks_u = (NU + 7) / 8;
    const int gat_blocks_i = (NI + 7) / 8;
    const int gemm_blocks_u = (NU + 63) / 64;
    const int gemm_blocks_i = (NI + 63) / 64;
    for (int l = 0; l < 3; ++l) {
        const float* b_uu = (const float*)d_in[12 + 6 * l + 1];
        const float* b_ui = (const float*)d_in[12 + 6 * l + 3];
        const float* b_iu = (const float*)d_in[12 + 6 * l + 5];
        __bf16* wh_uu = lw + (size_t)(l * 3 + 0) * 2 * 16384;
        __bf16* wh_ui = lw + (size_t)(l * 3 + 1) * 2 * 16384;
        __bf16* wh_iu = lw + (size_t)(l * 3 + 2) * 2 * 16384;
        const int relu = (l < 2) ? 1 : 0;

        // aggregate-first: m[d] = sum over in-edges of x[src]*rsqrt(deg_out[src])
        gather_scaled<<<gat_blocks_u, 256, 0, stream>>>(hu, rs_out_uu, rp_uu, ei_uu, m_uu, NU);
        gather_scaled<<<gat_blocks_i, 256, 0, stream>>>(hu, rs_out_ui, rp_ui, ei_ui, m_ui, NI);
        gather_scaled<<<gat_blocks_u, 256, 0, stream>>>(hi, rs_out_iu, rp_iu, ei_iu, m_iu, NU);
        // GEMM with fused epilogue: relu((m @ W) * rsqrt(deg_in) + b), summed per dst ntype
        gemm128_mfma<<<gemm_blocks_u, 256, 0, stream>>>(m_uu, HD, HD, NU,
            wh_uu, wh_uu + 16384, b_uu, rs_in_uu, relu, 0, hu);
        gemm128_mfma<<<gemm_blocks_u, 256, 0, stream>>>(m_iu, HD, HD, NU,
            wh_iu, wh_iu + 16384, b_iu, rs_in_iu, relu, 1, hu);
        gemm128_mfma<<<gemm_blocks_i, 256, 0, stream>>>(m_ui, HD, HD, NI,
            wh_ui, wh_ui + 16384, b_ui, rs_in_ui, relu, 0, hi);
    }
}